// Round 10
// baseline (3946.037 us; speedup 1.0000x reference)
//
#include <hip/hip_runtime.h>
#include <stdint.h>

#define NCAND 100000
#define NB    1024
#define DNUM  96
#define DM    256
#define DH    512
#define MCTX  96
#define LNEPS 1e-5f
#define ECAP  2560

typedef __bf16 bf16x8 __attribute__((ext_vector_type(8)));
typedef float  f32x4  __attribute__((ext_vector_type(4)));
typedef unsigned short u16x8 __attribute__((ext_vector_type(8)));
typedef unsigned short us;

__device__ __forceinline__ us f2bf(float x)
{
    unsigned u = __float_as_uint(x);
    unsigned r = u + 0x7FFFu + ((u >> 16) & 1u);   /* RNE */
    return (us)(r >> 16);
}
__device__ __forceinline__ float bfbits(us h)
{
    return __uint_as_float(((unsigned)h) << 16);
}

extern "C" __global__ __launch_bounds__(256)
void split_k(const float* X, us* Xh, us* Xl, long long n)
{
    long long i = (long long)blockIdx.x * 256 + threadIdx.x;
    if (i < n) {
        float x = X[i];
        us h = f2bf(x);
        Xh[i] = h;
        Xl[i] = f2bf(x - bfbits(h));
    }
}

/* pack weight W[Kd,Nd] (f32) into split-bf16 MFMA B-fragment order:
   elem i = ((jt*(Kd/32)+kt)*64+lane)*8+e <-> n=jt*16+(lane&15), k=kt*32+(lane>>4)*8+e */
extern "C" __global__ __launch_bounds__(256)
void packW_k(const float* W, us* Ph, us* Pl, int Kd, int Nd)
{
    int i = blockIdx.x * 256 + threadIdx.x;
    if (i >= Kd * Nd) return;
    int e = i & 7, lane = (i >> 3) & 63, r = i >> 9;
    int KT = Kd >> 5;
    int kt = r % KT, jt = r / KT;
    int n = jt * 16 + (lane & 15);
    int k = kt * 32 + (lane >> 4) * 8 + e;
    float x = W[(long long)k * Nd + n];
    us h = f2bf(x);
    Ph[i] = h;
    Pl[i] = f2bf(x - bfbits(h));
}

/* repack already-split rows R[N,Kd] into B-fragment order */
extern "C" __global__ __launch_bounds__(256)
void packR_k(const us* Rh, const us* Rl, us* Ph, us* Pl, int Kd, int total)
{
    int i = blockIdx.x * 256 + threadIdx.x;
    if (i >= total) return;
    int e = i & 7, lane = (i >> 3) & 63, r = i >> 9;
    int KT = Kd >> 5;
    int kt = r % KT, jt = r / KT;
    int n = jt * 16 + (lane & 15);
    int k = kt * 32 + (lane >> 4) * 8 + e;
    Ph[i] = Rh[(long long)n * Kd + k];
    Pl[i] = Rl[(long long)n * Kd + k];
}

/* =====================================================================
   Split-bf16 MFMA GEMM: A staged through LDS (coalesced global loads,
   conflict-free ds_read_b128 fragments), B pre-packed fragment order
   (contiguous 1KB/wave tile loads). Block = 4 waves, M-tile 64, N-tile 256
   (grid.y splits wider N). acc = Ah*Bh + Ah*Bl + Al*Bh (f32 accumulate).
   Modes: bias/split-resid/relu; f32|split|bf16 out; fused LN (grid.y==1,
   N==256); fused row-sumsq; gather-A (row = kq[row/96]-kc[gidx[row]],
   hi-only); sim transposed write (2*acc - colb[cand]). K%32==0.
   ===================================================================== */
extern "C" __global__ __launch_bounds__(256)
void gemm_d(const us* Ah, const us* Al, const us* BPh, const us* BPl,
            float* outF, us* outH, us* outL, us* outB16,
            const float* bias, const us* Rh, const us* Rl, int dorelu,
            const float* lng, const float* lnb, us* lnH, us* lnL,
            float* snOut,
            const us* Gqh, const us* Gql, const us* Gch, const us* Gcl,
            const int* gidx,
            float* simT, const float* colb,
            int M, int N, int K)
{
    __shared__ us Ahs[64][40];
    __shared__ us Als[64][40];
    int t = threadIdx.x, wave = t >> 6, lane = t & 63;
    int lm = lane & 15, lk = (lane >> 4) * 8, rb = (lane >> 4) * 4;
    int m0b = blockIdx.x * 64;
    int m0 = m0b + wave * 16;
    int n0 = blockIdx.y * 256;
    int KT = K >> 5;

    f32x4 acc[16];
#pragma unroll
    for (int j = 0; j < 16; j++)
        for (int e = 0; e < 4; e++) acc[j][e] = 0.0f;

    int sr = t >> 2;          /* staged row 0..63 */
    int ss = (t & 3) * 8;     /* k-segment: 0,8,16,24 */
    int srow = m0b + sr;
    int gb = 0, gc = 0;
    if (gidx && srow < M) { gb = srow / MCTX; gc = gidx[srow]; }

    for (int kt = 0; kt < KT; kt++) {
        int k0 = kt * 32;
        u16x8 ah8 = {0,0,0,0,0,0,0,0}, al8 = ah8;
        if (srow < M) {
            if (!gidx) {
                ah8 = *(const u16x8*)(Ah + (long long)srow * K + k0 + ss);
                al8 = *(const u16x8*)(Al + (long long)srow * K + k0 + ss);
            } else {
                u16x8 qh = *(const u16x8*)(Gqh + (long long)gb * DM + k0 + ss);
                u16x8 ql = *(const u16x8*)(Gql + (long long)gb * DM + k0 + ss);
                u16x8 ch = *(const u16x8*)(Gch + (long long)gc * DM + k0 + ss);
                u16x8 cl = *(const u16x8*)(Gcl + (long long)gc * DM + k0 + ss);
#pragma unroll
                for (int e = 0; e < 8; e++) {
                    float v = (bfbits(qh[e]) + bfbits(ql[e]))
                            - (bfbits(ch[e]) + bfbits(cl[e]));
                    ah8[e] = f2bf(v);
                }
            }
        }
        __syncthreads();   /* previous iteration's LDS reads done */
        *(u16x8*)&Ahs[sr][ss] = ah8;
        *(u16x8*)&Als[sr][ss] = al8;
        __syncthreads();
        bf16x8 fah = *(const bf16x8*)&Ahs[wave * 16 + lm][lk];
        bf16x8 fal = *(const bf16x8*)&Als[wave * 16 + lm][lk];
#pragma unroll
        for (int j = 0; j < 16; j++) {
            long long bo = ((long long)((n0 >> 4) + j) * KT + kt) * 512 + lane * 8;
            u16x8 bu  = *(const u16x8*)(BPh + bo);
            u16x8 blu = *(const u16x8*)(BPl + bo);
            bf16x8 fbh = *(bf16x8*)&bu;
            bf16x8 fbl = *(bf16x8*)&blu;
            acc[j] = __builtin_amdgcn_mfma_f32_16x16x32_bf16(fah, fbh, acc[j], 0, 0, 0);
            acc[j] = __builtin_amdgcn_mfma_f32_16x16x32_bf16(fah, fbl, acc[j], 0, 0, 0);
            if (!gidx)
                acc[j] = __builtin_amdgcn_mfma_f32_16x16x32_bf16(fal, fbh, acc[j], 0, 0, 0);
        }
    }

    /* C/D layout: col = lane&15 (within j-tile), row = (lane>>4)*4 + e */
    if (simT) {
        if (m0 < M) {
#pragma unroll
            for (int j = 0; j < 16; j++) {
                int q = n0 + j * 16 + lm;
                f32x4 v;
                for (int e = 0; e < 4; e++)
                    v[e] = 2.0f * acc[j][e] - colb[m0 + rb + e];
                *(f32x4*)(simT + (long long)q * NCAND + m0 + rb) = v;
            }
        }
        return;
    }

#pragma unroll
    for (int j = 0; j < 16; j++) {
        int col = n0 + j * 16 + lm;
        float bc = bias ? bias[col] : 0.0f;
        for (int e = 0; e < 4; e++) {
            int row = m0 + rb + e;
            float v = acc[j][e] + bc;
            if (row < M) {
                long long oix = (long long)row * N + col;
                if (Rh) v += bfbits(Rh[oix]) + bfbits(Rl[oix]);
                if (dorelu && v < 0.0f) v = 0.0f;
                if (outF)   outF[oix] = v;
                if (outB16) outB16[oix] = f2bf(v);
                if (outH) { us h = f2bf(v); outH[oix] = h; outL[oix] = f2bf(v - bfbits(h)); }
            } else {
                if (dorelu && v < 0.0f) v = 0.0f;
            }
            acc[j][e] = v;
        }
    }

    if (lng || snOut) {
        float mu4[4], rs4[4];
        for (int e = 0; e < 4; e++) {
            float s1 = 0.0f, s2 = 0.0f;
#pragma unroll
            for (int j = 0; j < 16; j++) { float v = acc[j][e]; s1 += v; s2 += v * v; }
            for (int o = 1; o < 16; o <<= 1) {
                s1 += __shfl_xor(s1, o, 64);
                s2 += __shfl_xor(s2, o, 64);
            }
            int row = m0 + rb + e;
            if (snOut && lm == 0 && row < M) snOut[row] = s2;
            float mu = s1 * (1.0f / 256.0f);
            float var = s2 * (1.0f / 256.0f) - mu * mu;
            mu4[e] = mu;
            rs4[e] = rsqrtf(var + LNEPS);
        }
        if (lng) {
#pragma unroll
            for (int j = 0; j < 16; j++) {
                int col = n0 + j * 16 + lm;
                float g = lng[col], bb = lnb[col];
                for (int e = 0; e < 4; e++) {
                    int row = m0 + rb + e;
                    if (row >= M) continue;
                    float y = (acc[j][e] - mu4[e]) * rs4[e] * g + bb;
                    long long oix = (long long)row * N + col;
                    us h = f2bf(y);
                    lnH[oix] = h;
                    lnL[oix] = f2bf(y - bfbits(h));
                }
            }
        }
    }
}

__device__ unsigned fmapf(float f)
{
    unsigned u = __float_as_uint(f);
    return u ^ (unsigned)(((int)u >> 31) | (int)0x80000000);
}
__device__ float funmap(unsigned key)
{
    unsigned uu = (key & 0x80000000u) ? (key ^ 0x80000000u) : ~key;
    return __uint_as_float(uu);
}

/* exact top-96 + softmax. 2 global scans (12-bit histogram + capture),
   then radix refinement on the LDS candidate list (8/8/4 bits).
   Full-scan fallback if the level-1 tie bucket exceeds ECAP.
   Ties at full 32-bit threshold -> smallest index. */
extern "C" __global__ __launch_bounds__(1024)
void topk_k(const float* S, int q0, int* out_idx, float* out_p)
{
    int t = threadIdx.x;
    const float* row = S + (long long)blockIdx.x * NCAND;
    const float4* row4 = (const float4*)row;
    __shared__ int hist[4096];
    __shared__ unsigned ek0[ECAP]; __shared__ int ei0[ECAP];
    __shared__ unsigned ek1[ECAP]; __shared__ int ei1[ECAP];
    __shared__ float gv[MCTX]; __shared__ int gi[MCTX];
    __shared__ float pr[MCTX];
    __shared__ int gcnt, ecnt, encnt, sh_b, sh_need;

    if (t == 0) { gcnt = 0; ecnt = 0; }
    for (int i = t; i < 4096; i += 1024) hist[i] = 0;
    __syncthreads();

    /* scan 1: 12-bit histogram */
    for (int c = t; c < NCAND / 4; c += 1024) {
        float4 v = row4[c];
        atomicAdd(&hist[fmapf(v.x) >> 20], 1);
        atomicAdd(&hist[fmapf(v.y) >> 20], 1);
        atomicAdd(&hist[fmapf(v.z) >> 20], 1);
        atomicAdd(&hist[fmapf(v.w) >> 20], 1);
    }
    __syncthreads();
    if (t == 0) {
        int cum = 0, b = 4095;
        for (; b >= 0; b--) { cum += hist[b]; if (cum >= MCTX) break; }
        sh_b = b; sh_need = MCTX - (cum - hist[b]);
    }
    __syncthreads();
    unsigned b1 = (unsigned)sh_b;
    /* scan 2: capture G (bin > b1, <96 guaranteed) and E (bin == b1) */
    for (int c = t; c < NCAND / 4; c += 1024) {
        float4 v = row4[c];
        float vv[4]; vv[0] = v.x; vv[1] = v.y; vv[2] = v.z; vv[3] = v.w;
        for (int e = 0; e < 4; e++) {
            unsigned key = fmapf(vv[e]);
            unsigned bin = key >> 20;
            if (bin > b1) {
                int p = atomicAdd(&gcnt, 1);
                gv[p] = vv[e]; gi[p] = c * 4 + e;
            } else if (bin == b1) {
                int p = atomicAdd(&ecnt, 1);
                if (p < ECAP) { ek0[p] = key; ei0[p] = c * 4 + e; }
            }
        }
    }
    __syncthreads();
    unsigned pref = b1 << 20;
    int shifts[3]; shifts[0] = 12; shifts[1] = 4; shifts[2] = 0;
    int widths[3]; widths[0] = 256; widths[1] = 256; widths[2] = 16;

    if (ecnt <= ECAP) {
        /* LDS refinement */
        int n = ecnt;
        unsigned* ksrc = ek0; int* isrc = ei0;
        unsigned* kdst = ek1; int* idst = ei1;
        for (int lvl = 0; lvl < 3; lvl++) {
            int sh = shifts[lvl], nb = widths[lvl];
            unsigned msk = (unsigned)(nb - 1);
            for (int i = t; i < nb; i += 1024) hist[i] = 0;
            if (t == 0) encnt = 0;
            __syncthreads();
            for (int i = t; i < n; i += 1024)
                atomicAdd(&hist[(ksrc[i] >> sh) & msk], 1);
            __syncthreads();
            if (t == 0) {
                int need = sh_need, cum = 0, b = nb - 1;
                for (; b >= 0; b--) { cum += hist[b]; if (cum >= need) break; }
                sh_b = b; sh_need = need - (cum - hist[b]);
            }
            __syncthreads();
            unsigned bl = (unsigned)sh_b;
            for (int i = t; i < n; i += 1024) {
                unsigned bin = (ksrc[i] >> sh) & msk;
                if (bin > bl) {
                    int p = atomicAdd(&gcnt, 1);
                    gv[p] = funmap(ksrc[i]); gi[p] = isrc[i];
                } else if (bin == bl) {
                    int p = atomicAdd(&encnt, 1);
                    kdst[p] = ksrc[i]; idst[p] = isrc[i];
                }
            }
            __syncthreads();
            pref |= bl << sh;
            n = encnt;
            unsigned* tk = ksrc; ksrc = kdst; kdst = tk;
            int* ti = isrc; isrc = idst; idst = ti;
            __syncthreads();
        }
        /* remaining n entries have key == pref exactly: smallest indices win */
        if (t == 0) {
            int need = sh_need;
            float tv = funmap(pref);
            for (int s = 0; s < need; s++) {
                int best = 0x7FFFFFFF, bp = -1;
                for (int i2 = 0; i2 < n; i2++) if (isrc[i2] < best) { best = isrc[i2]; bp = i2; }
                int p = gcnt + s;
                if (bp >= 0) { isrc[bp] = 0x7FFFFFFF; gv[p] = tv; gi[p] = best; }
                else         { gv[p] = -3.0e38f; gi[p] = 0; }
            }
        }
        __syncthreads();
    } else {
        /* fallback: full-scan refinement */
        unsigned mask = 0xFFF00000u;
        for (int lvl = 0; lvl < 3; lvl++) {
            int sh = shifts[lvl], nb = widths[lvl];
            unsigned msk = (unsigned)(nb - 1);
            for (int i = t; i < nb; i += 1024) hist[i] = 0;
            __syncthreads();
            for (int c = t; c < NCAND; c += 1024) {
                unsigned key = fmapf(row[c]);
                if ((key & mask) == pref) atomicAdd(&hist[(key >> sh) & msk], 1);
            }
            __syncthreads();
            if (t == 0) {
                int need = sh_need, cum = 0, b = nb - 1;
                for (; b >= 0; b--) { cum += hist[b]; if (cum >= need) break; }
                sh_b = b; sh_need = need - (cum - hist[b]);
            }
            __syncthreads();
            pref |= ((unsigned)sh_b) << sh;
            mask |= msk << sh;
            __syncthreads();
        }
        if (t == 0) encnt = 0;
        __syncthreads();
        for (int c = t; c < NCAND; c += 1024) {
            unsigned key = fmapf(row[c]);
            if ((key >> 20) == b1) {
                if (key > pref) {
                    int p = atomicAdd(&gcnt, 1);
                    gv[p] = row[c]; gi[p] = c;
                } else if (key == pref) {
                    int p = atomicAdd(&encnt, 1);
                    if (p < ECAP) ei1[p] = c;
                }
            }
        }
        __syncthreads();
        if (t == 0) {
            int need = sh_need;
            int n = encnt; if (n > ECAP) n = ECAP;
            float tv = funmap(pref);
            for (int s = 0; s < need; s++) {
                int best = 0x7FFFFFFF, bp = -1;
                for (int i2 = 0; i2 < n; i2++) if (ei1[i2] < best) { best = ei1[i2]; bp = i2; }
                int p = gcnt + s;
                if (bp >= 0) { ei1[bp] = 0x7FFFFFFF; gv[p] = tv; gi[p] = best; }
                else         { gv[p] = -3.0e38f; gi[p] = 0; }
            }
        }
        __syncthreads();
    }

    /* softmax over the 96 (order arbitrary: downstream permutation-invariant) */
    if (t == 0) {
        float mx = -3.4e38f;
        for (int i = 0; i < MCTX; i++) if (gv[i] > mx) mx = gv[i];
        float sum = 0.0f;
        for (int i = 0; i < MCTX; i++) { float e = expf(gv[i] - mx); pr[i] = e; sum += e; }
        float inv = 1.0f / sum;
        for (int i = 0; i < MCTX; i++) pr[i] *= inv;
    }
    __syncthreads();
    if (t < MCTX) {
        long long o = (long long)(q0 + blockIdx.x) * MCTX + t;
        out_idx[o] = gi[t];
        out_p[o]   = pr[t];
    }
}

extern "C" __global__ __launch_bounds__(256)
void ybar_k(const float* P, const int* idx, const float* y, float* ybar)
{
    __shared__ float sred[256];
    int b = blockIdx.x, t = threadIdx.x;
    float v = 0.0f;
    if (t < MCTX) v = P[(long long)b * MCTX + t] * y[idx[(long long)b * MCTX + t]];
    sred[t] = v; __syncthreads();
    for (int s = 128; s > 0; s >>= 1) { if (t < s) sred[t] += sred[t + s]; __syncthreads(); }
    if (t == 0) ybar[b] = sred[0];
}

/* tier A: u[b,j] = sum_m p_m * relu(Pq[b,j] - R[idx_m, j]) */
extern "C" __global__ __launch_bounds__(512)
void wsum2_k(const float* Pq, const float* R, const float* P, const int* idx, float* u)
{
    __shared__ float pl[MCTX];
    __shared__ int ix[MCTX];
    int b = blockIdx.x, j = threadIdx.x;
    if (j < MCTX) {
        pl[j] = P[(long long)b * MCTX + j];
        ix[j] = idx[(long long)b * MCTX + j];
    }
    __syncthreads();
    float pb = Pq[(long long)b * DH + j];
    float a = 0.0f;
    for (int m = 0; m < MCTX; m++) {
        float d = pb - R[(long long)ix[m] * DH + j];
        a += pl[m] * (d > 0.0f ? d : 0.0f);
    }
    u[(long long)b * DH + j] = a;
}

/* tier B: u[b,j] = sum_m p_m * U[(b,m),j], U plain bf16 */
extern "C" __global__ __launch_bounds__(512)
void wsum_k(const us* U, const float* P, float* u)
{
    __shared__ float pl[MCTX];
    int b = blockIdx.x, j = threadIdx.x;
    if (j < MCTX) pl[j] = P[(long long)b * MCTX + j];
    __syncthreads();
    const us* Ub = U + (long long)b * MCTX * DH;
    float acc = 0.0f;
    for (int m = 0; m < MCTX; m++) acc += pl[m] * bfbits(Ub[(long long)m * DH + j]);
    u[(long long)b * DH + j] = acc;
}

extern "C" __global__ __launch_bounds__(256)
void mixprep_sp(us* h2h, us* h2l, const float* ybar,
                const float* Wy, const float* by, const float* bt2)
{
    int b = blockIdx.x, d = threadIdx.x;
    long long i = (long long)b * DM + d;
    float v = bfbits(h2h[i]) + bfbits(h2l[i]) + ybar[b] * Wy[d] + by[d] + bt2[d];
    us h = f2bf(v);
    h2h[i] = h;
    h2l[i] = f2bf(v - bfbits(h));
}

extern "C" __global__ __launch_bounds__(256)
void head_k(const float* X, const float* g, const float* bln, const float* Wh,
            const float* bh, float* out)
{
    __shared__ float sred[256];
    int r = blockIdx.x, t = threadIdx.x;
    float x = X[(long long)r * DM + t];
    sred[t] = x; __syncthreads();
    for (int s = 128; s > 0; s >>= 1) { if (t < s) sred[t] += sred[t + s]; __syncthreads(); }
    float mu = sred[0] * (1.0f / DM); __syncthreads();
    float d = x - mu;
    sred[t] = d * d; __syncthreads();
    for (int s = 128; s > 0; s >>= 1) { if (t < s) sred[t] += sred[t + s]; __syncthreads(); }
    float var = sred[0] * (1.0f / DM); __syncthreads();
    float ln = d * rsqrtf(var + LNEPS) * g[t] + bln[t];
    float rl = (ln > 0.0f) ? ln : 0.0f;
    sred[t] = rl * Wh[t]; __syncthreads();
    for (int s = 128; s > 0; s >>= 1) { if (t < s) sred[t] += sred[t + s]; __syncthreads(); }
    if (t == 0) out[r] = sred[0] + bh[0];
}

#define ZU (us*)0
#define ZCU (const us*)0
#define ZF (float*)0
#define ZCF (const float*)0
#define ZI (const int*)0

extern "C" void kernel_launch(void* const* d_in, const int* in_sizes, int n_in,
                              void* d_out, int out_size, void* d_ws, size_t ws_size,
                              hipStream_t stream)
{
    const float* x_num  = (const float*)d_in[0];
    const float* cand_x = (const float*)d_in[1];
    const float* cand_y = (const float*)d_in[2];
    const float* W_in = (const float*)d_in[4];
    const float* b_in = (const float*)d_in[5];
    const float* We1  = (const float*)d_in[6];
    const float* be1  = (const float*)d_in[7];
    const float* We2  = (const float*)d_in[8];
    const float* be2  = (const float*)d_in[9];
    const float* g_m  = (const float*)d_in[10];
    const float* b_m  = (const float*)d_in[11];
    const float* Ws   = (const float*)d_in[12];
    const float* bs   = (const float*)d_in[13];
    const float* Wy   = (const float*)d_in[14];
    const float* by   = (const float*)d_in[15];
    const float* Wt1  = (const float*)d_in[16];
    const float* Wt2  = (const float*)d_in[17];
    const float* bt2  = (const float*)d_in[18];
    const float* Wp1  = (const float*)d_in[19];
    const float* bp1  = (const float*)d_in[20];
    const float* Wp2  = (const float*)d_in[21];
    const float* bp2  = (const float*)d_in[22];
    const float* g_h  = (const float*)d_in[23];
    const float* b_h  = (const float*)d_in[24];
    const float* Wh   = (const float*)d_in[25];
    const float* bh   = (const float*)d_in[26];
    float* out = (float*)d_out;

    char* p = (char*)d_ws;
    us* WinPh = (us*)p; p += 256*96*2;   us* WinPl = (us*)p; p += 256*96*2;
    us* We1Ph = (us*)p; p += 512*256*2;  us* We1Pl = (us*)p; p += 512*256*2;
    us* We2Ph = (us*)p; p += 256*512*2;  us* We2Pl = (us*)p; p += 256*512*2;
    us* WsPh  = (us*)p; p += 256*256*2;  us* WsPl  = (us*)p; p += 256*256*2;
    us* Wt1Ph = (us*)p; p += 512*256*2;  us* Wt1Pl = (us*)p; p += 512*256*2;
    us* Wt2Ph = (us*)p; p += 256*512*2;  us* Wt2Pl = (us*)p; p += 256*512*2;
    us* Wp1Ph = (us*)p; p += 512*256*2;  us* Wp1Pl = (us*)p; p += 512*256*2;
    us* Wp2Ph = (us*)p; p += 256*512*2;  us* Wp2Pl = (us*)p; p += 256*512*2;
    us* XNh  = (us*)p; p += (long long)NB*DNUM*2;  us* XNl  = (us*)p; p += (long long)NB*DNUM*2;
    us* HQ1h = (us*)p; p += (long long)NB*DM*2;    us* HQ1l = (us*)p; p += (long long)NB*DM*2;
    us* TQh  = (us*)p; p += (long long)NB*DH*2;    us* TQl  = (us*)p; p += (long long)NB*DH*2;
    us* HQ2h = (us*)p; p += (long long)NB*DM*2;    us* HQ2l = (us*)p; p += (long long)NB*DM*2;
    us* LNQh = (us*)p; p += (long long)NB*DM*2;    us* LNQl = (us*)p; p += (long long)NB*DM*2;
    us* KQh  = (us*)p; p += (long long)NB*DM*2;    us* KQl  = (us*)p; p += (long long)NB*DM*2;
    us* KQPh = (us*)p; p += (long long)NB*DM*2;    us* KQPl = (us*)p; p += (long long)NB*DM*2;
    us* XQh  = (us*)p; p += (long long)NB*DM*2;    us* XQl  = (us*)p; p += (long long)NB*DM*2;
    us* UQvh = (us*)p; p += (long long)NB*DH*2;    us* UQvl = (us*)p; p += (long long)NB*DH*2;
    float* UQv  = (float*)p; p += (long long)NB*DH*4;
    float* Pq   = (float*)p; p += (long long)NB*DH*4;
    float* XQ2f = (float*)p; p += (long long)NB*DM*4;
    float* YB   = (float*)p; p += (long long)NB*4;
    int*   IDX  = (int*)p;   p += (long long)NB*MCTX*4;
    float* PRB  = (float*)p; p += (long long)NB*MCTX*4;
    us* KCh = (us*)p; p += (long long)NCAND*DM*2;  us* KCl = (us*)p; p += (long long)NCAND*DM*2;
    float* SC = (float*)p; p += (long long)NCAND*4;

    size_t used = (size_t)(p - (char*)d_ws);
    long long avail = (ws_size > used + 4096) ? (long long)(ws_size - used - 4096) : 0;
    int EC = 6250;
    if      (avail >= 243300000LL) EC = 50000;
    else if (avail >= 141000000LL) EC = 25000;
    else if (avail >=  89700000LL) EC = 12500;
    int QS = (avail >= 204800000LL) ? 512 : 256;
    int tierA = (avail >= 204800000LL) ? 1 : 0;
    int VC = (avail >= 100700000LL) ? 1024 : 512;

    char* AR = p;
    us* CXh = (us*)AR;
    us* CXl = CXh + (long long)NCAND*DNUM;
    char* EB = AR + (long long)NCAND*DNUM*4;
    us* Hch  = (us*)EB;                              us* Hcl  = Hch + (long long)EC*DM;
    us* Tch  = (us*)(EB + (long long)EC*DM*4);       us* Tcl  = Tch + (long long)EC*DH;
    us* LNch = (us*)(EB + (long long)EC*(DM+DH)*4);  us* LNcl = LNch + (long long)EC*DM;
    float* Sb = (float*)AR;
    float* R  = (float*)AR;
    us* Ub = (us*)AR;

    dim3 blk(256);

    /* ---- one-time weight packs + activation splits ---- */
    packW_k<<<dim3((DNUM*DM+255)/256), blk, 0, stream>>>(W_in, WinPh, WinPl, DNUM, DM);
    packW_k<<<dim3((DM*DH+255)/256), blk, 0, stream>>>(We1, We1Ph, We1Pl, DM, DH);
    packW_k<<<dim3((DH*DM+255)/256), blk, 0, stream>>>(We2, We2Ph, We2Pl, DH, DM);
    packW_k<<<dim3((DM*DM+255)/256), blk, 0, stream>>>(Ws,  WsPh,  WsPl,  DM, DM);
    packW_k<<<dim3((DM*DH+255)/256), blk, 0, stream>>>(Wt1, Wt1Ph, Wt1Pl, DM, DH);
    packW_k<<<dim3((DH*DM+255)/256), blk, 0, stream>>>(Wt2, Wt2Ph, Wt2Pl, DH, DM);
    packW_k<<<dim3((DM*DH+255)/256), blk, 0, stream>>>(Wp1, Wp1Ph, Wp1Pl, DM, DH);
    packW_k<<<dim3((DH*DM+255)/256), blk, 0, stream>>>(Wp2, Wp2Ph, Wp2Pl, DH, DM);
    split_k<<<dim3((NB*DNUM+255)/256), blk, 0, stream>>>(x_num, XNh, XNl, (long long)NB*DNUM);
    split_k<<<dim3((NCAND*DNUM+255)/256), blk, 0, stream>>>(cand_x, CXh, CXl, (long long)NCAND*DNUM);

    /* ---- query encode ---- */
    gemm_d<<<dim3(NB/64, 1), blk, 0, stream>>>(XNh, XNl, WinPh, WinPl,
        ZF, HQ1h, HQ1l, ZU, b_in, ZCU, ZCU, 0, ZCF, ZCF, ZU, ZU, ZF,
        ZCU, ZCU, ZCU, ZCU, ZI, ZF, ZCF, NB, DM, DNUM);
    gemm_d<<<dim3(NB/64, 2), blk, 0, stream>>>(HQ1h, HQ1l, We1Ph, We1Pl,
        ZF, TQh, TQl, ZU, be1, ZCU, ZCU, 1, ZCF, ZCF, ZU, ZU, ZF,
        ZCU, ZCU, ZCU, ZCU, ZI, ZF, ZCF, NB, DH, DM);
    gemm_d<<<dim3(NB/64, 1), blk, 0, stream>>>(TQh, TQl, We2Ph, We2Pl,
        ZF, HQ2h, HQ2l, ZU, be2, HQ1h, HQ1l, 0, g_m, b_m, LNQh, LNQl, ZF,
        ZCU, ZCU, ZCU, ZCU, ZI, ZF, ZCF, NB, DM, DH);
    gemm_d<<<dim3(NB/64, 1), blk, 0, stream>>>(LNQh, LNQl, WsPh, WsPl,
        ZF, KQh, KQl, ZU, bs, ZCU, ZCU, 0, ZCF, ZCF, ZU, ZU, ZF,
        ZCU, ZCU, ZCU, ZCU, ZI, ZF, ZCF, NB, DM, DM);
    packR_k<<<dim3((NB*DM+255)/256), blk, 0, stream>>>(KQh, KQl, KQPh, KQPl, DM, NB*DM);

    /* ---- candidate encode (fused LN, fused ||k||^2) ---- */
    for (int c0 = 0; c0 < NCAND; c0 += EC) {
        int gx = (EC + 63) / 64;
        gemm_d<<<dim3(gx, 1), blk, 0, stream>>>(CXh + (long long)c0*DNUM, CXl + (long long)c0*DNUM,
            WinPh, WinPl, ZF, Hch, Hcl, ZU, b_in, ZCU, ZCU, 0, ZCF, ZCF, ZU, ZU, ZF,
            ZCU, ZCU, ZCU, ZCU, ZI, ZF, ZCF, EC, DM, DNUM);
        gemm_d<<<dim3(gx, 2), blk, 0, stream>>>(Hch, Hcl, We1Ph, We1Pl,
            ZF, Tch, Tcl, ZU, be1, ZCU, ZCU, 1, ZCF, ZCF, ZU, ZU, ZF,
            ZCU, ZCU, ZCU, ZCU, ZI, ZF, ZCF, EC, DH, DM);
        gemm_d<<<dim3(gx, 1), blk, 0, stream>>>(Tch, Tcl, We2Ph, We2Pl,
            ZF, ZU, ZU, ZU, be2, Hch, Hcl, 0, g_m, b_m, LNch, LNcl, ZF,
            ZCU, ZCU, ZCU, ZCU, ZI, ZF, ZCF, EC, DM, DH);
        gemm_d<<<dim3(gx, 1), blk, 0, stream>>>(LNch, LNcl, WsPh, WsPl,
            ZF, KCh + (long long)c0*DM, KCl + (long long)c0*DM, ZU, bs, ZCU, ZCU, 0,
            ZCF, ZCF, ZU, ZU, SC + c0,
            ZCU, ZCU, ZCU, ZCU, ZI, ZF, ZCF, EC, DM, DM);
    }

    /* ---- sim (2*k.ck - ||ck||^2, transposed write) + exact top-96 ---- */
    for (int q0 = 0; q0 < NB; q0 += QS) {
        gemm_d<<<dim3((NCAND + 63) / 64, QS / 256), blk, 0, stream>>>(KCh, KCl,
            KQPh + (long long)q0*DM, KQPl + (long long)q0*DM,
            ZF, ZU, ZU, ZU, ZCF, ZCU, ZCU, 0, ZCF, ZCF, ZU, ZU, ZF,
            ZCU, ZCU, ZCU, ZCU, ZI, Sb, SC, NCAND, QS, DM);
        topk_k<<<dim3(QS), dim3(1024), 0, stream>>>(Sb, q0, IDX, PRB);
    }

    /* ---- value aggregation ---- */
    ybar_k<<<dim3(NB), blk, 0, stream>>>(PRB, IDX, cand_y, YB);
    gemm_d<<<dim3(NB/64, 2), blk, 0, stream>>>(KQh, KQl, Wt1Ph, Wt1Pl,
        Pq, ZU, ZU, ZU, ZCF, ZCU, ZCU, 0, ZCF, ZCF, ZU, ZU, ZF,
        ZCU, ZCU, ZCU, ZCU, ZI, ZF, ZCF, NB, DH, DM);
    if (tierA) {
        gemm_d<<<dim3((NCAND + 63) / 64, 2), blk, 0, stream>>>(KCh, KCl, Wt1Ph, Wt1Pl,
            R, ZU, ZU, ZU, ZCF, ZCU, ZCU, 0, ZCF, ZCF, ZU, ZU, ZF,
            ZCU, ZCU, ZCU, ZCU, ZI, ZF, ZCF, NCAND, DH, DM);
        wsum2_k<<<dim3(NB), dim3(512), 0, stream>>>(Pq, R, PRB, IDX, UQv);
    } else {
        for (int v0 = 0; v0 < NB; v0 += VC) {
            gemm_d<<<dim3((VC * MCTX) / 64, 2), blk, 0, stream>>>(ZCU, ZCU, Wt1Ph, Wt1Pl,
                ZF, ZU, ZU, Ub, ZCF, ZCU, ZCU, 1, ZCF, ZCF, ZU, ZU, ZF,
                KQh + (long long)v0*DM, KQl + (long long)v0*DM, KCh, KCl,
                IDX + (long long)v0*MCTX, ZF, ZCF, VC * MCTX, DH, DM);
            wsum_k<<<dim3(VC), dim3(512), 0, stream>>>(Ub, PRB + (long long)v0*MCTX,
                                                       UQv + (long long)v0*DH);
        }
    }
    split_k<<<dim3((NB*DH+255)/256), blk, 0, stream>>>(UQv, UQvh, UQvl, (long long)NB*DH);
    mixprep_sp<<<dim3(NB), blk, 0, stream>>>(HQ2h, HQ2l, YB, Wy, by, bt2);
    gemm_d<<<dim3(NB/64, 1), blk, 0, stream>>>(UQvh, UQvl, Wt2Ph, Wt2Pl,
        ZF, XQh, XQl, ZU, ZCF, HQ2h, HQ2l, 0, ZCF, ZCF, ZU, ZU, ZF,
        ZCU, ZCU, ZCU, ZCU, ZI, ZF, ZCF, NB, DM, DH);

    /* ---- predictor block + head ---- */
    gemm_d<<<dim3(NB/64, 2), blk, 0, stream>>>(XQh, XQl, Wp1Ph, Wp1Pl,
        ZF, TQh, TQl, ZU, bp1, ZCU, ZCU, 1, ZCF, ZCF, ZU, ZU, ZF,
        ZCU, ZCU, ZCU, ZCU, ZI, ZF, ZCF, NB, DH, DM);
    gemm_d<<<dim3(NB/64, 1), blk, 0, stream>>>(TQh, TQl, Wp2Ph, Wp2Pl,
        XQ2f, ZU, ZU, ZU, bp2, XQh, XQl, 0, ZCF, ZCF, ZU, ZU, ZF,
        ZCU, ZCU, ZCU, ZCU, ZI, ZF, ZCF, NB, DM, DH);
    head_k<<<dim3(NB), blk, 0, stream>>>(XQ2f, g_h, b_h, Wh, bh, out);
}

// Round 11
// 3462.893 us; speedup vs baseline: 1.1395x; 1.1395x over previous
//
#include <hip/hip_runtime.h>
#include <stdint.h>

#define NCAND 100000
#define NB    1024
#define DNUM  96
#define DM    256
#define DH    512
#define MCTX  96
#define LNEPS 1e-5f

typedef __bf16 bf16x8 __attribute__((ext_vector_type(8)));
typedef float  f32x4  __attribute__((ext_vector_type(4)));
typedef unsigned short u16x8 __attribute__((ext_vector_type(8)));
typedef unsigned short us;

__device__ __forceinline__ us f2bf(float x)
{
    unsigned u = __float_as_uint(x);
    unsigned r = u + 0x7FFFu + ((u >> 16) & 1u);   /* RNE */
    return (us)(r >> 16);
}
__device__ __forceinline__ float bfbits(us h)
{
    return __uint_as_float(((unsigned)h) << 16);
}

extern "C" __global__ __launch_bounds__(256)
void split_k(const float* X, us* Xh, us* Xl, long long n)
{
    long long i = (long long)blockIdx.x * 256 + threadIdx.x;
    if (i < n) {
        float x = X[i];
        us h = f2bf(x);
        Xh[i] = h;
        Xl[i] = f2bf(x - bfbits(h));
    }
}

/* pack weight W[Kd,Nd] (f32) into split-bf16 MFMA B-fragment order:
   elem i = ((jt*(Kd/32)+kt)*64+lane)*8+e <-> n=jt*16+(lane&15), k=kt*32+(lane>>4)*8+e */
extern "C" __global__ __launch_bounds__(256)
void packW_k(const float* W, us* Ph, us* Pl, int Kd, int Nd)
{
    int i = blockIdx.x * 256 + threadIdx.x;
    if (i >= Kd * Nd) return;
    int e = i & 7, lane = (i >> 3) & 63, r = i >> 9;
    int KT = Kd >> 5;
    int kt = r % KT, jt = r / KT;
    int n = jt * 16 + (lane & 15);
    int k = kt * 32 + (lane >> 4) * 8 + e;
    float x = W[(long long)k * Nd + n];
    us h = f2bf(x);
    Ph[i] = h;
    Pl[i] = f2bf(x - bfbits(h));
}

/* repack already-split rows R[N,Kd] into B-fragment order */
extern "C" __global__ __launch_bounds__(256)
void packR_k(const us* Rh, const us* Rl, us* Ph, us* Pl, int Kd, int total)
{
    int i = blockIdx.x * 256 + threadIdx.x;
    if (i >= total) return;
    int e = i & 7, lane = (i >> 3) & 63, r = i >> 9;
    int KT = Kd >> 5;
    int kt = r % KT, jt = r / KT;
    int n = jt * 16 + (lane & 15);
    int k = kt * 32 + (lane >> 4) * 8 + e;
    Ph[i] = Rh[(long long)n * Kd + k];
    Pl[i] = Rl[(long long)n * Kd + k];
}

/* =====================================================================
   Direct-fragment split-bf16 MFMA GEMM, wave tile M64xN64.
   Block = 4 waves side-by-side in N: block tile M=64, N=256;
   grid = (ceil(M/64), N/256). Wave w owns cols n0+w*64..+64 (4 j-tiles)
   and rows m0b..+64 (4 i-tiles). B pre-packed fragment order: each
   B-tile load is one contiguous 1KB/wave transaction, 4 distinct
   j-tiles per wave (no cross-wave B redundancy). A row-major split
   (strided fragment loads, L1-shared across waves). No K-loop LDS.
   acc = Ah*Bh + Ah*Bl + Al*Bh (f32, rel err ~1e-4).
   Modes: bias/split-resid/relu; f32|split|bf16 out; fused LN via
   cross-wave LDS stats (grid.y==1, N==256); fused row-sumsq; gather-A
   (row = kq[row/96]-kc[gidx[row]], hi-only, 2-pass); sim transposed
   write (2*acc - colb[cand], M%16==0). K%32==0.
   ===================================================================== */
extern "C" __global__ __launch_bounds__(256)
void gemm_d(const us* Ah, const us* Al, const us* BPh, const us* BPl,
            float* outF, us* outH, us* outL, us* outB16,
            const float* bias, const us* Rh, const us* Rl, int dorelu,
            const float* lng, const float* lnb, us* lnH, us* lnL,
            float* snOut,
            const us* Gqh, const us* Gql, const us* Gch, const us* Gcl,
            const int* gidx,
            float* simT, const float* colb,
            int M, int N, int K)
{
    __shared__ float red1[256];
    __shared__ float red2[256];
    __shared__ float mu_s[64];
    __shared__ float rs_s[64];
    int t = threadIdx.x, wave = t >> 6, lane = t & 63;
    int lm = lane & 15, lk = (lane >> 4) * 8, rb = (lane >> 4) * 4;
    int m0b = blockIdx.x * 64;
    int n0 = blockIdx.y * 256;
    int KT = K >> 5;
    int jt0 = (n0 >> 4) + wave * 4;

    f32x4 acc[4][4];
#pragma unroll
    for (int i = 0; i < 4; i++)
#pragma unroll
        for (int j = 0; j < 4; j++)
            for (int e = 0; e < 4; e++) acc[i][j][e] = 0.0f;

    int gb4[4], gc4[4];
    if (gidx) {
#pragma unroll
        for (int i = 0; i < 4; i++) {
            int grow = m0b + i * 16 + lm;
            if (grow < M) { gb4[i] = grow / MCTX; gc4[i] = gidx[grow]; }
            else          { gb4[i] = 0; gc4[i] = 0; }
        }
    }

    for (int kt = 0; kt < KT; kt++) {
        int k0 = kt * 32;
        bf16x8 fah[4], fal[4];
#pragma unroll
        for (int i = 0; i < 4; i++) {
            int arow = m0b + i * 16 + lm;
            u16x8 ah8 = {0,0,0,0,0,0,0,0}, al8 = ah8;
            if (arow < M) {
                if (!gidx) {
                    ah8 = *(const u16x8*)(Ah + (long long)arow * K + k0 + lk);
                    al8 = *(const u16x8*)(Al + (long long)arow * K + k0 + lk);
                } else {
                    u16x8 qh = *(const u16x8*)(Gqh + (long long)gb4[i] * DM + k0 + lk);
                    u16x8 ql = *(const u16x8*)(Gql + (long long)gb4[i] * DM + k0 + lk);
                    u16x8 ch = *(const u16x8*)(Gch + (long long)gc4[i] * DM + k0 + lk);
                    u16x8 cl = *(const u16x8*)(Gcl + (long long)gc4[i] * DM + k0 + lk);
#pragma unroll
                    for (int e = 0; e < 8; e++) {
                        float v = (bfbits(qh[e]) + bfbits(ql[e]))
                                - (bfbits(ch[e]) + bfbits(cl[e]));
                        ah8[e] = f2bf(v);
                    }
                }
            }
            fah[i] = *(bf16x8*)&ah8;
            fal[i] = *(bf16x8*)&al8;
        }
#pragma unroll
        for (int j = 0; j < 4; j++) {
            long long bo = ((long long)(jt0 + j) * KT + kt) * 512 + lane * 8;
            u16x8 bu  = *(const u16x8*)(BPh + bo);
            u16x8 blu = *(const u16x8*)(BPl + bo);
            bf16x8 fbh = *(bf16x8*)&bu;
            bf16x8 fbl = *(bf16x8*)&blu;
#pragma unroll
            for (int i = 0; i < 4; i++) {
                acc[i][j] = __builtin_amdgcn_mfma_f32_16x16x32_bf16(fah[i], fbh, acc[i][j], 0, 0, 0);
                acc[i][j] = __builtin_amdgcn_mfma_f32_16x16x32_bf16(fah[i], fbl, acc[i][j], 0, 0, 0);
                if (!gidx)
                    acc[i][j] = __builtin_amdgcn_mfma_f32_16x16x32_bf16(fal[i], fbh, acc[i][j], 0, 0, 0);
            }
        }
    }

    /* C/D layout: col = lane&15 (within j-tile), row = (lane>>4)*4 + e */
    if (simT) {
#pragma unroll
        for (int i = 0; i < 4; i++) {
            int cb = m0b + i * 16;
            if (cb >= M) break;
#pragma unroll
            for (int j = 0; j < 4; j++) {
                int q = n0 + wave * 64 + j * 16 + lm;
                f32x4 v;
                for (int e = 0; e < 4; e++)
                    v[e] = 2.0f * acc[i][j][e] - colb[cb + rb + e];
                *(f32x4*)(simT + (long long)q * NCAND + cb + rb) = v;
            }
        }
        return;
    }

    /* pass 1: bias/resid/relu into acc + primary outputs */
#pragma unroll
    for (int j = 0; j < 4; j++) {
        int col = n0 + wave * 64 + j * 16 + lm;
        float bc = bias ? bias[col] : 0.0f;
#pragma unroll
        for (int i = 0; i < 4; i++) {
            for (int e = 0; e < 4; e++) {
                int row = m0b + i * 16 + rb + e;
                float v = acc[i][j][e] + bc;
                if (row < M) {
                    long long oix = (long long)row * N + col;
                    if (Rh) v += bfbits(Rh[oix]) + bfbits(Rl[oix]);
                    if (dorelu && v < 0.0f) v = 0.0f;
                    if (outF)   outF[oix] = v;
                    if (outB16) outB16[oix] = f2bf(v);
                    if (outH) { us h = f2bf(v); outH[oix] = h; outL[oix] = f2bf(v - bfbits(h)); }
                } else {
                    if (dorelu && v < 0.0f) v = 0.0f;
                }
                acc[i][j][e] = v;
            }
        }
    }

    if (lng || snOut) {
        /* per-wave partials over this wave's 64 cols, cross-wave LDS reduce */
#pragma unroll
        for (int i = 0; i < 4; i++) {
            for (int e = 0; e < 4; e++) {
                int lr = i * 16 + rb + e;
                float s1 = 0.0f, s2 = 0.0f;
#pragma unroll
                for (int j = 0; j < 4; j++) { float v = acc[i][j][e]; s1 += v; s2 += v * v; }
                for (int o = 1; o < 16; o <<= 1) {
                    s1 += __shfl_xor(s1, o, 64);
                    s2 += __shfl_xor(s2, o, 64);
                }
                if (lm == 0) { red1[lr * 4 + wave] = s1; red2[lr * 4 + wave] = s2; }
            }
        }
        __syncthreads();
        if (t < 64) {
            float a = red1[t*4] + red1[t*4+1] + red1[t*4+2] + red1[t*4+3];
            float b2 = red2[t*4] + red2[t*4+1] + red2[t*4+2] + red2[t*4+3];
            if (lng) {
                float mu = a * (1.0f / 256.0f);
                float var = b2 * (1.0f / 256.0f) - mu * mu;
                mu_s[t] = mu;
                rs_s[t] = rsqrtf(var + LNEPS);
            }
            if (snOut && (m0b + t) < M) snOut[m0b + t] = b2;
        }
        __syncthreads();
        if (lng) {
#pragma unroll
            for (int j = 0; j < 4; j++) {
                int col = n0 + wave * 64 + j * 16 + lm;
                float g = lng[col], bb = lnb[col];
#pragma unroll
                for (int i = 0; i < 4; i++) {
                    for (int e = 0; e < 4; e++) {
                        int lr = i * 16 + rb + e;
                        int row = m0b + lr;
                        if (row >= M) continue;
                        float y = (acc[i][j][e] - mu_s[lr]) * rs_s[lr] * g + bb;
                        long long oix = (long long)row * N + col;
                        us h = f2bf(y);
                        lnH[oix] = h;
                        lnL[oix] = f2bf(y - bfbits(h));
                    }
                }
            }
        }
    }
}

__device__ unsigned fmapf(float f)
{
    unsigned u = __float_as_uint(f);
    return u ^ (unsigned)(((int)u >> 31) | (int)0x80000000);
}

/* exact top-96 (radix select 4x8-bit, ties -> smallest index) + softmax
   (R8/R9-proven version) */
extern "C" __global__ __launch_bounds__(1024)
void topk_k(const float* S, int q0, int* out_idx, float* out_p)
{
    int t = threadIdx.x;
    const float* row = S + (long long)blockIdx.x * NCAND;
    const float4* row4 = (const float4*)row;
    __shared__ int hist8[8][256];
    __shared__ unsigned sh_prefix;
    __shared__ int sh_want, cntG, cntE;
    __shared__ int   gidx[128];
    __shared__ float gval[128];
    __shared__ int   eqi[2048];
    __shared__ float vals[MCTX];
    __shared__ int   inds[MCTX];
    __shared__ float pr[MCTX];

    if (t == 0) { sh_prefix = 0u; sh_want = MCTX; cntG = 0; cntE = 0; }

    for (int lvl = 0; lvl < 4; lvl++) {
        int shift = 24 - 8 * lvl;
        for (int i = t; i < 2048; i += 1024) ((int*)hist8)[i] = 0;
        __syncthreads();
        unsigned prefix = sh_prefix;
        unsigned mask = (lvl == 0) ? 0u : (0xFFFFFFFFu << (shift + 8));
        int* hrow = hist8[t & 7];
        for (int c = t; c < NCAND / 4; c += 1024) {
            float4 v = row4[c];
            unsigned k0 = fmapf(v.x), k1 = fmapf(v.y), k2 = fmapf(v.z), k3 = fmapf(v.w);
            if ((k0 & mask) == prefix) atomicAdd(&hrow[(k0 >> shift) & 255], 1);
            if ((k1 & mask) == prefix) atomicAdd(&hrow[(k1 >> shift) & 255], 1);
            if ((k2 & mask) == prefix) atomicAdd(&hrow[(k2 >> shift) & 255], 1);
            if ((k3 & mask) == prefix) atomicAdd(&hrow[(k3 >> shift) & 255], 1);
        }
        __syncthreads();
        if (t < 256) {
            int s = 0;
            for (int g2 = 1; g2 < 8; g2++) s += hist8[g2][t];
            hist8[0][t] += s;
        }
        __syncthreads();
        if (t == 0) {
            int want = sh_want, cum = 0;
            for (int b2 = 255; b2 >= 0; b2--) {
                cum += hist8[0][b2];
                if (cum >= want) {
                    sh_want = want - (cum - hist8[0][b2]);
                    sh_prefix = prefix | ((unsigned)b2 << shift);
                    break;
                }
            }
        }
        __syncthreads();
    }
    unsigned T = sh_prefix;
    for (int c = t; c < NCAND / 4; c += 1024) {
        float4 v = row4[c];
        float vv[4]; vv[0] = v.x; vv[1] = v.y; vv[2] = v.z; vv[3] = v.w;
        for (int e = 0; e < 4; e++) {
            unsigned key = fmapf(vv[e]);
            if (key > T) {
                int p = atomicAdd(&cntG, 1);
                if (p < 128) { gidx[p] = c * 4 + e; gval[p] = vv[e]; }
            } else if (key == T) {
                int p = atomicAdd(&cntE, 1);
                if (p < 2048) eqi[p] = c * 4 + e;
            }
        }
    }
    __syncthreads();
    if (t == 0) {
        int nG = cntG; if (nG > MCTX) nG = MCTX;
        int nE = cntE; if (nE > 2048) nE = 2048;
        int need = MCTX - nG;
        for (int i = 0; i < nG; i++) { inds[i] = gidx[i]; vals[i] = gval[i]; }
        for (int s = 0; s < need; s++) {
            int best = 0x7FFFFFFF, bp = -1;
            for (int e = 0; e < nE; e++) if (eqi[e] < best) { best = eqi[e]; bp = e; }
            if (bp >= 0) { eqi[bp] = 0x7FFFFFFF; inds[nG + s] = best; vals[nG + s] = row[best]; }
            else         { inds[nG + s] = 0;     vals[nG + s] = -3.0e38f; }
        }
        float mx = -3.4e38f;
        for (int i = 0; i < MCTX; i++) if (vals[i] > mx) mx = vals[i];
        float sum = 0.0f;
        for (int i = 0; i < MCTX; i++) { float e = expf(vals[i] - mx); pr[i] = e; sum += e; }
        float inv = 1.0f / sum;
        for (int i = 0; i < MCTX; i++) pr[i] *= inv;
    }
    __syncthreads();
    if (t < MCTX) {
        long long o = (long long)(q0 + blockIdx.x) * MCTX + t;
        out_idx[o] = inds[t];
        out_p[o]   = pr[t];
    }
}

extern "C" __global__ __launch_bounds__(256)
void ybar_k(const float* P, const int* idx, const float* y, float* ybar)
{
    __shared__ float sred[256];
    int b = blockIdx.x, t = threadIdx.x;
    float v = 0.0f;
    if (t < MCTX) v = P[(long long)b * MCTX + t] * y[idx[(long long)b * MCTX + t]];
    sred[t] = v; __syncthreads();
    for (int s = 128; s > 0; s >>= 1) { if (t < s) sred[t] += sred[t + s]; __syncthreads(); }
    if (t == 0) ybar[b] = sred[0];
}

/* tier A: u[b,j] = sum_m p_m * relu(Pq[b,j] - R[idx_m, j]) */
extern "C" __global__ __launch_bounds__(512)
void wsum2_k(const float* Pq, const float* R, const float* P, const int* idx, float* u)
{
    __shared__ float pl[MCTX];
    __shared__ int ix[MCTX];
    int b = blockIdx.x, j = threadIdx.x;
    if (j < MCTX) {
        pl[j] = P[(long long)b * MCTX + j];
        ix[j] = idx[(long long)b * MCTX + j];
    }
    __syncthreads();
    float pb = Pq[(long long)b * DH + j];
    float a = 0.0f;
    for (int m = 0; m < MCTX; m++) {
        float d = pb - R[(long long)ix[m] * DH + j];
        a += pl[m] * (d > 0.0f ? d : 0.0f);
    }
    u[(long long)b * DH + j] = a;
}

/* tier B: u[b,j] = sum_m p_m * U[(b,m),j], U plain bf16 */
extern "C" __global__ __launch_bounds__(512)
void wsum_k(const us* U, const float* P, float* u)
{
    __shared__ float pl[MCTX];
    int b = blockIdx.x, j = threadIdx.x;
    if (j < MCTX) pl[j] = P[(long long)b * MCTX + j];
    __syncthreads();
    const us* Ub = U + (long long)b * MCTX * DH;
    float acc = 0.0f;
    for (int m = 0; m < MCTX; m++) acc += pl[m] * bfbits(Ub[(long long)m * DH + j]);
    u[(long long)b * DH + j] = acc;
}

extern "C" __global__ __launch_bounds__(256)
void mixprep_sp(us* h2h, us* h2l, const float* ybar,
                const float* Wy, const float* by, const float* bt2)
{
    int b = blockIdx.x, d = threadIdx.x;
    long long i = (long long)b * DM + d;
    float v = bfbits(h2h[i]) + bfbits(h2l[i]) + ybar[b] * Wy[d] + by[d] + bt2[d];
    us h = f2bf(v);
    h2h[i] = h;
    h2l[i] = f2bf(v - bfbits(h));
}

extern "C" __global__ __launch_bounds__(256)
void head_k(const float* X, const float* g, const float* bln, const float* Wh,
            const float* bh, float* out)
{
    __shared__ float sred[256];
    int r = blockIdx.x, t = threadIdx.x;
    float x = X[(long long)r * DM + t];
    sred[t] = x; __syncthreads();
    for (int s = 128; s > 0; s >>= 1) { if (t < s) sred[t] += sred[t + s]; __syncthreads(); }
    float mu = sred[0] * (1.0f / DM); __syncthreads();
    float d = x - mu;
    sred[t] = d * d; __syncthreads();
    for (int s = 128; s > 0; s >>= 1) { if (t < s) sred[t] += sred[t + s]; __syncthreads(); }
    float var = sred[0] * (1.0f / DM); __syncthreads();
    float ln = d * rsqrtf(var + LNEPS) * g[t] + bln[t];
    float rl = (ln > 0.0f) ? ln : 0.0f;
    sred[t] = rl * Wh[t]; __syncthreads();
    for (int s = 128; s > 0; s >>= 1) { if (t < s) sred[t] += sred[t + s]; __syncthreads(); }
    if (t == 0) out[r] = sred[0] + bh[0];
}

#define ZU (us*)0
#define ZCU (const us*)0
#define ZF (float*)0
#define ZCF (const float*)0
#define ZI (const int*)0

extern "C" void kernel_launch(void* const* d_in, const int* in_sizes, int n_in,
                              void* d_out, int out_size, void* d_ws, size_t ws_size,
                              hipStream_t stream)
{
    const float* x_num  = (const float*)d_in[0];
    const float* cand_x = (const float*)d_in[1];
    const float* cand_y = (const float*)d_in[2];
    const float* W_in = (const float*)d_in[4];
    const float* b_in = (const float*)d_in[5];
    const float* We1  = (const float*)d_in[6];
    const float* be1  = (const float*)d_in[7];
    const float* We2  = (const float*)d_in[8];
    const float* be2  = (const float*)d_in[9];
    const float* g_m  = (const float*)d_in[10];
    const float* b_m  = (const float*)d_in[11];
    const float* Ws   = (const float*)d_in[12];
    const float* bs   = (const float*)d_in[13];
    const float* Wy   = (const float*)d_in[14];
    const float* by   = (const float*)d_in[15];
    const float* Wt1  = (const float*)d_in[16];
    const float* Wt2  = (const float*)d_in[17];
    const float* bt2  = (const float*)d_in[18];
    const float* Wp1  = (const float*)d_in[19];
    const float* bp1  = (const float*)d_in[20];
    const float* Wp2  = (const float*)d_in[21];
    const float* bp2  = (const float*)d_in[22];
    const float* g_h  = (const float*)d_in[23];
    const float* b_h  = (const float*)d_in[24];
    const float* Wh   = (const float*)d_in[25];
    const float* bh   = (const float*)d_in[26];
    float* out = (float*)d_out;

    char* p = (char*)d_ws;
    us* WinPh = (us*)p; p += 256*96*2;   us* WinPl = (us*)p; p += 256*96*2;
    us* We1Ph = (us*)p; p += 512*256*2;  us* We1Pl = (us*)p; p += 512*256*2;
    us* We2Ph = (us*)p; p += 256*512*2;  us* We2Pl = (us*)p; p += 256*512*2;
    us* WsPh  = (us*)p; p += 256*256*2;  us* WsPl  = (us*)p; p += 256*256*2;
    us* Wt1Ph = (us*)p; p += 512*256*2;  us* Wt1Pl = (us*)p; p += 512*256*2;
    us* Wt2Ph = (us*)p; p += 256*512*2;  us* Wt2Pl = (us*)p; p += 256*512*2;
    us* Wp1Ph = (us*)p; p += 512*256*2;  us* Wp1Pl = (us*)p; p += 512*256*2;
    us* Wp2Ph = (us*)p; p += 256*512*2;  us* Wp2Pl = (us*)p; p += 256*512*2;
    us* XNh  = (us*)p; p += (long long)NB*DNUM*2;  us* XNl  = (us*)p; p += (long long)NB*DNUM*2;
    us* HQ1h = (us*)p; p += (long long)NB*DM*2;    us* HQ1l = (us*)p; p += (long long)NB*DM*2;
    us* TQh  = (us*)p; p += (long long)NB*DH*2;    us* TQl  = (us*)p; p += (long long)NB*DH*2;
    us* HQ2h = (us*)p; p += (long long)NB*DM*2;    us* HQ2l = (us*)p; p += (long long)NB*DM*2;
    us* LNQh = (us*)p; p += (long long)NB*DM*2;    us* LNQl = (us*)p; p += (long long)NB*DM*2;
    us* KQh  = (us*)p; p += (long long)NB*DM*2;    us* KQl  = (us*)p; p += (long long)NB*DM*2;
    us* KQPh = (us*)p; p += (long long)NB*DM*2;    us* KQPl = (us*)p; p += (long long)NB*DM*2;
    us* XQh  = (us*)p; p += (long long)NB*DM*2;    us* XQl  = (us*)p; p += (long long)NB*DM*2;
    us* UQvh = (us*)p; p += (long long)NB*DH*2;    us* UQvl = (us*)p; p += (long long)NB*DH*2;
    float* UQv  = (float*)p; p += (long long)NB*DH*4;
    float* Pq   = (float*)p; p += (long long)NB*DH*4;
    float* XQ2f = (float*)p; p += (long long)NB*DM*4;
    float* YB   = (float*)p; p += (long long)NB*4;
    int*   IDX  = (int*)p;   p += (long long)NB*MCTX*4;
    float* PRB  = (float*)p; p += (long long)NB*MCTX*4;
    us* KCh = (us*)p; p += (long long)NCAND*DM*2;  us* KCl = (us*)p; p += (long long)NCAND*DM*2;
    float* SC = (float*)p; p += (long long)NCAND*4;

    size_t used = (size_t)(p - (char*)d_ws);
    long long avail = (ws_size > used + 4096) ? (long long)(ws_size - used - 4096) : 0;
    int EC = 6250;
    if      (avail >= 243300000LL) EC = 50000;
    else if (avail >= 141000000LL) EC = 25000;
    else if (avail >=  89700000LL) EC = 12500;
    int QS = (avail >= 204800000LL) ? 512 : 256;
    int tierA = (avail >= 204800000LL) ? 1 : 0;
    int VC = (avail >= 100700000LL) ? 1024 : 512;

    char* AR = p;
    us* CXh = (us*)AR;
    us* CXl = CXh + (long long)NCAND*DNUM;
    char* EB = AR + (long long)NCAND*DNUM*4;
    us* Hch  = (us*)EB;                              us* Hcl  = Hch + (long long)EC*DM;
    us* Tch  = (us*)(EB + (long long)EC*DM*4);       us* Tcl  = Tch + (long long)EC*DH;
    us* LNch = (us*)(EB + (long long)EC*(DM+DH)*4);  us* LNcl = LNch + (long long)EC*DM;
    float* Sb = (float*)AR;
    float* R  = (float*)AR;
    us* Ub = (us*)AR;

    dim3 blk(256);

    /* ---- one-time weight packs + activation splits ---- */
    packW_k<<<dim3((DNUM*DM+255)/256), blk, 0, stream>>>(W_in, WinPh, WinPl, DNUM, DM);
    packW_k<<<dim3((DM*DH+255)/256), blk, 0, stream>>>(We1, We1Ph, We1Pl, DM, DH);
    packW_k<<<dim3((DH*DM+255)/256), blk, 0, stream>>>(We2, We2Ph, We2Pl, DH, DM);
    packW_k<<<dim3((DM*DM+255)/256), blk, 0, stream>>>(Ws,  WsPh,  WsPl,  DM, DM);
    packW_k<<<dim3((DM*DH+255)/256), blk, 0, stream>>>(Wt1, Wt1Ph, Wt1Pl, DM, DH);
    packW_k<<<dim3((DH*DM+255)/256), blk, 0, stream>>>(Wt2, Wt2Ph, Wt2Pl, DH, DM);
    packW_k<<<dim3((DM*DH+255)/256), blk, 0, stream>>>(Wp1, Wp1Ph, Wp1Pl, DM, DH);
    packW_k<<<dim3((DH*DM+255)/256), blk, 0, stream>>>(Wp2, Wp2Ph, Wp2Pl, DH, DM);
    split_k<<<dim3((NB*DNUM+255)/256), blk, 0, stream>>>(x_num, XNh, XNl, (long long)NB*DNUM);
    split_k<<<dim3((NCAND*DNUM+255)/256), blk, 0, stream>>>(cand_x, CXh, CXl, (long long)NCAND*DNUM);

    /* ---- query encode ---- */
    gemm_d<<<dim3(NB/64, 1), blk, 0, stream>>>(XNh, XNl, WinPh, WinPl,
        ZF, HQ1h, HQ1l, ZU, b_in, ZCU, ZCU, 0, ZCF, ZCF, ZU, ZU, ZF,
        ZCU, ZCU, ZCU, ZCU, ZI, ZF, ZCF, NB, DM, DNUM);
    gemm_d<<<dim3(NB/64, 2), blk, 0, stream>>>(HQ1h, HQ1l, We1Ph, We1Pl,
        ZF, TQh, TQl, ZU, be1, ZCU, ZCU, 1, ZCF, ZCF, ZU, ZU, ZF,
        ZCU, ZCU, ZCU, ZCU, ZI, ZF, ZCF, NB, DH, DM);
    gemm_d<<<dim3(NB/64, 1), blk, 0, stream>>>(TQh, TQl, We2Ph, We2Pl,
        ZF, HQ2h, HQ2l, ZU, be2, HQ1h, HQ1l, 0, g_m, b_m, LNQh, LNQl, ZF,
        ZCU, ZCU, ZCU, ZCU, ZI, ZF, ZCF, NB, DM, DH);
    gemm_d<<<dim3(NB/64, 1), blk, 0, stream>>>(LNQh, LNQl, WsPh, WsPl,
        ZF, KQh, KQl, ZU, bs, ZCU, ZCU, 0, ZCF, ZCF, ZU, ZU, ZF,
        ZCU, ZCU, ZCU, ZCU, ZI, ZF, ZCF, NB, DM, DM);
    packR_k<<<dim3((NB*DM+255)/256), blk, 0, stream>>>(KQh, KQl, KQPh, KQPl, DM, NB*DM);

    /* ---- candidate encode (fused LN, fused ||k||^2) ---- */
    for (int c0 = 0; c0 < NCAND; c0 += EC) {
        int gx = (EC + 63) / 64;
        gemm_d<<<dim3(gx, 1), blk, 0, stream>>>(CXh + (long long)c0*DNUM, CXl + (long long)c0*DNUM,
            WinPh, WinPl, ZF, Hch, Hcl, ZU, b_in, ZCU, ZCU, 0, ZCF, ZCF, ZU, ZU, ZF,
            ZCU, ZCU, ZCU, ZCU, ZI, ZF, ZCF, EC, DM, DNUM);
        gemm_d<<<dim3(gx, 2), blk, 0, stream>>>(Hch, Hcl, We1Ph, We1Pl,
            ZF, Tch, Tcl, ZU, be1, ZCU, ZCU, 1, ZCF, ZCF, ZU, ZU, ZF,
            ZCU, ZCU, ZCU, ZCU, ZI, ZF, ZCF, EC, DH, DM);
        gemm_d<<<dim3(gx, 1), blk, 0, stream>>>(Tch, Tcl, We2Ph, We2Pl,
            ZF, ZU, ZU, ZU, be2, Hch, Hcl, 0, g_m, b_m, LNch, LNcl, ZF,
            ZCU, ZCU, ZCU, ZCU, ZI, ZF, ZCF, EC, DM, DH);
        gemm_d<<<dim3(gx, 1), blk, 0, stream>>>(LNch, LNcl, WsPh, WsPl,
            ZF, KCh + (long long)c0*DM, KCl + (long long)c0*DM, ZU, bs, ZCU, ZCU, 0,
            ZCF, ZCF, ZU, ZU, SC + c0,
            ZCU, ZCU, ZCU, ZCU, ZI, ZF, ZCF, EC, DM, DM);
    }

    /* ---- sim (2*k.ck - ||ck||^2, transposed write) + exact top-96 ---- */
    for (int q0 = 0; q0 < NB; q0 += QS) {
        gemm_d<<<dim3((NCAND + 63) / 64, QS / 256), blk, 0, stream>>>(KCh, KCl,
            KQPh + (long long)q0*DM, KQPl + (long long)q0*DM,
            ZF, ZU, ZU, ZU, ZCF, ZCU, ZCU, 0, ZCF, ZCF, ZU, ZU, ZF,
            ZCU, ZCU, ZCU, ZCU, ZI, Sb, SC, NCAND, QS, DM);
        topk_k<<<dim3(QS), dim3(1024), 0, stream>>>(Sb, q0, IDX, PRB);
    }

    /* ---- value aggregation ---- */
    ybar_k<<<dim3(NB), blk, 0, stream>>>(PRB, IDX, cand_y, YB);
    gemm_d<<<dim3(NB/64, 2), blk, 0, stream>>>(KQh, KQl, Wt1Ph, Wt1Pl,
        Pq, ZU, ZU, ZU, ZCF, ZCU, ZCU, 0, ZCF, ZCF, ZU, ZU, ZF,
        ZCU, ZCU, ZCU, ZCU, ZI, ZF, ZCF, NB, DH, DM);
    if (tierA) {
        gemm_d<<<dim3((NCAND + 63) / 64, 2), blk, 0, stream>>>(KCh, KCl, Wt1Ph, Wt1Pl,
            R, ZU, ZU, ZU, ZCF, ZCU, ZCU, 0, ZCF, ZCF, ZU, ZU, ZF,
            ZCU, ZCU, ZCU, ZCU, ZI, ZF, ZCF, NCAND, DH, DM);
        wsum2_k<<<dim3(NB), dim3(512), 0, stream>>>(Pq, R, PRB, IDX, UQv);
    } else {
        for (int v0 = 0; v0 < NB; v0 += VC) {
            gemm_d<<<dim3((VC * MCTX) / 64, 2), blk, 0, stream>>>(ZCU, ZCU, Wt1Ph, Wt1Pl,
                ZF, ZU, ZU, Ub, ZCF, ZCU, ZCU, 1, ZCF, ZCF, ZU, ZU, ZF,
                KQh + (long long)v0*DM, KQl + (long long)v0*DM, KCh, KCl,
                IDX + (long long)v0*MCTX, ZF, ZCF, VC * MCTX, DH, DM);
            wsum_k<<<dim3(VC), dim3(512), 0, stream>>>(Ub, PRB + (long long)v0*MCTX,
                                                       UQv + (long long)v0*DH);
        }
    }
    split_k<<<dim3((NB*DH+255)/256), blk, 0, stream>>>(UQv, UQvh, UQvl, (long long)NB*DH);
    mixprep_sp<<<dim3(NB), blk, 0, stream>>>(HQ2h, HQ2l, YB, Wy, by, bt2);
    gemm_d<<<dim3(NB/64, 1), blk, 0, stream>>>(UQvh, UQvl, Wt2Ph, Wt2Pl,
        ZF, XQh, XQl, ZU, ZCF, HQ2h, HQ2l, 0, ZCF, ZCF, ZU, ZU, ZF,
        ZCU, ZCU, ZCU, ZCU, ZI, ZF, ZCF, NB, DM, DH);

    /* ---- predictor block + head ---- */
    gemm_d<<<dim3(NB/64, 2), blk, 0, stream>>>(XQh, XQl, Wp1Ph, Wp1Pl,
        ZF, TQh, TQl, ZU, bp1, ZCU, ZCU, 1, ZCF, ZCF, ZU, ZU, ZF,
        ZCU, ZCU, ZCU, ZCU, ZI, ZF, ZCF, NB, DH, DM);
    gemm_d<<<dim3(NB/64, 1), blk, 0, stream>>>(TQh, TQl, Wp2Ph, Wp2Pl,
        XQ2f, ZU, ZU, ZU, bp2, XQh, XQl, 0, ZCF, ZCF, ZU, ZU, ZF,
        ZCU, ZCU, ZCU, ZCU, ZI, ZF, ZCF, NB, DM, DH);
    head_k<<<dim3(NB), blk, 0, stream>>>(XQ2f, g_h, b_h, Wh, bh, out);
}